// Round 14
// baseline (53.515 us; speedup 1.0000x reference)
//
#include <hip/hip_runtime.h>
#include <math.h>

#define LAT_CONST  ((float)(5.0 * 0.03 / 200.0 + 0.06))   // 0.06075
#define GRAD_CONST ((float)(1.0 / 0.06))                  // 16.666666...
#define SEND_CONST ((float)(2.0 / 3.0))                   // 0.666666...

// Wide table (step 1, global/L1 packed): t = x2_init*f in [-24, 24].
#define NW   2048
#define LOW_ (-24.f)
#define HIW_ (24.f)
#define HW_  ((HIW_ - LOW_) / (float)NW)
#define IHW_ ((float)NW / (HIW_ - LOW_))
#define CW_  (-LOW_ * IHW_)
// Narrow range (steps 2..10): x2 in (0,1), f in (-5.8, 1].
#define N2   2048
#define LO2  (-6.25f)
#define HI2  (1.25f)
#define H2   ((HI2 - LO2) / (float)N2)
#define IH2  ((float)N2 / (HI2 - LO2))
#define C2   (-LO2 * IH2)
#define MID2 (-2.5f)          // (LO2+HI2)/2
#define HALF2 (3.75f)         // (HI2-LO2)/2
#define IHALF2 (1.f / 3.75f)

#define GSZ   2080      // f32 entries built per table (padded)
#define GPCK  2064      // packed u32 entries (gathers use <= N2+1 = 2049)
#define MCH   64        // Chebyshev sample nodes
#define NCOEF 28        // Chebyshev coefficients kept (degree 27)

typedef unsigned int u32;

__device__ __forceinline__ u32 bfpack(float a, float b) {
    u32 ua = __float_as_uint(a), ub = __float_as_uint(b);
    ua = (ua + 0x7fffu + ((ua >> 16) & 1u)) >> 16;          // RNE to bf16
    ub = (ub + 0x7fffu + ((ub >> 16) & 1u)) & 0xffff0000u;  // RNE, keep high half
    return (ua & 0xffffu) | ub;
}

__device__ __forceinline__ float lerp_pk(u32 u, float fr) {
    float e0 = __uint_as_float(u << 16);
    float e1 = __uint_as_float(u & 0xffff0000u);
    return fmaf(e1 - e0, fr, e0);
}

// ---------------- Kernel 1: build tables + Chebyshev node samples ----------
// 64 entries/block, layer-2 j-split across 8 waves. Entries:
// [0,GSZ) wide table, [GSZ,2GSZ) narrow table, [2GSZ,2GSZ+64) cheb nodes.
__global__ __launch_bounds__(512)
void build_table_kernel(const float* __restrict__ W1, const float* __restrict__ b1,
                        const float* __restrict__ W2, const float* __restrict__ b2,
                        const float* __restrict__ W3, const float* __restrict__ b3,
                        float* __restrict__ g1, float* __restrict__ g2,
                        float* __restrict__ fch)
{
    __shared__ float pl[8][64];

    const int lane = threadIdx.x & 63;
    const int w    = threadIdx.x >> 6;                // 0..7
    const int i    = blockIdx.x * 64 + lane;          // 0 .. 2*GSZ+63

    float t;
    if (i < GSZ)          t = LOW_ + (float)i * HW_;
    else if (i < 2 * GSZ) t = LO2 + (float)(i - GSZ) * H2;
    else {                                            // Chebyshev node
        int j = i - 2 * GSZ;                          // 0..63
        float th = ((float)j + 0.5f) * ((float)M_PI / (float)MCH);
        t = MID2 + HALF2 * cosf(th);
    }

    float x4 = t + LAT_CONST;
    float x5 = t * SEND_CONST;
    float x3 = x4 * GRAD_CONST;

    float h1v[64];
#pragma unroll
    for (int j = 0; j < 64; ++j) {
        float acc = b1[j];
        acc = fmaf(x3, W1[j],       acc);
        acc = fmaf(x4, W1[64 + j],  acc);
        acc = fmaf(x5, W1[128 + j], acc);
        h1v[j] = fmaxf(acc, 0.f);
    }

    const int j0 = w * 8;
    float acc[8];
#pragma unroll
    for (int u = 0; u < 8; ++u) acc[u] = b2[j0 + u];
#pragma unroll
    for (int k = 0; k < 64; ++k) {
        const float* __restrict__ w2r = W2 + k * 64 + j0;
#pragma unroll
        for (int u = 0; u < 8; ++u)
            acc[u] = fmaf(h1v[k], w2r[u], acc[u]);
    }
    float partial = 0.f;
#pragma unroll
    for (int u = 0; u < 8; ++u)
        partial = fmaf(fmaxf(acc[u], 0.f), W3[j0 + u], partial);

    pl[w][lane] = partial;
    __syncthreads();

    if (w == 0) {
        float logit = b3[0] + (((pl[0][lane] + pl[1][lane]) + (pl[2][lane] + pl[3][lane]))
                             + ((pl[4][lane] + pl[5][lane]) + (pl[6][lane] + pl[7][lane])));
        float g = 1.f / (1.f + expf(-logit));
        if (i < GSZ)          g1[i] = g;
        else if (i < 2 * GSZ) g2[i - GSZ] = g;
        else                  fch[i - 2 * GSZ] = g;
    }
}

// ---------------- Kernel 1b: DCT fit (28 coeffs) + pack tables -------------
__global__ __launch_bounds__(256)
void fit_pack_kernel(const float* __restrict__ g1, const float* __restrict__ g2,
                     const float* __restrict__ fch,
                     u32* __restrict__ g1p, u32* __restrict__ g2p,
                     float* __restrict__ cb)
{
    int i = blockIdx.x * blockDim.x + threadIdx.x;
    if (i < GPCK) {
        g1p[i] = bfpack(g1[i], g1[i + 1]);
        g2p[i] = bfpack(g2[i], g2[i + 1]);
    }
    if (blockIdx.x == 0 && threadIdx.x < NCOEF) {
        int k = threadIdx.x;
        float s = 0.f;
        for (int j = 0; j < MCH; ++j) {
            float th = ((float)j + 0.5f) * ((float)M_PI / (float)MCH);
            s = fmaf(fch[j], cosf((float)k * th), s);
        }
        float c = s * (2.f / (float)MCH);
        cb[k] = (k == 0) ? 0.5f * c : c;   // store c0/2 for Clenshaw epilogue
    }
}

// ---------------- Kernel 2: persistent pipelined row update ----------------
// Steps 2..9 are a degree-27 Clenshaw poly on the VALU (coeffs wave-uniform
// -> SGPR); only steps 1 (global packed table) and 10 (LDS packed table)
// gather. Gathers per row: 10 -> 2.
#define CHUNK 256
#define BLOCK 256
#define MAXBLK 1792       // 7 blocks/CU * 256 CU (LDS 22.6 KB -> 7/CU)

typedef __attribute__((address_space(3))) u32 lds_u32_t;
typedef __attribute__((address_space(1))) const u32 glb_u32_t;

__device__ __forceinline__ void gload16(const void* g, void* l) {
    __builtin_amdgcn_global_load_lds((glb_u32_t*)g, (lds_u32_t*)l, 16, 0, 0);
}
__device__ __forceinline__ void gload4(const void* g, void* l) {
    __builtin_amdgcn_global_load_lds((glb_u32_t*)g, (lds_u32_t*)l, 4, 0, 0);
}

__global__ __launch_bounds__(BLOCK)
void rows_kernel(const float* __restrict__ x, const u32* __restrict__ g1p,
                 const u32* __restrict__ g2p, const float* __restrict__ cb,
                 float* __restrict__ out, int B, int nChunks, int grid)
{
    __shared__ u32 tn[GPCK];                           // 8256 B
    __shared__ __align__(16) float buf[2][CHUNK * 7];  // 14336 B (total 22592)

    const int tid = threadIdx.x;
    const long long b = blockIdx.x;
    const int cb_ = (int)(b * (long long)nChunks / grid);
    const int ce  = (int)((b + 1) * (long long)nChunks / grid);

    // Wave-uniform Chebyshev coefficients -> scalar regs.
    float c[NCOEF];
#pragma unroll
    for (int k = 0; k < NCOEF; ++k) c[k] = cb[k];

    // Prologue: async-DMA first chunk into buf0.
    {
        int rows0 = min(CHUNK, B - cb_ * CHUNK);
        int nfl0  = rows0 * 7;
        int nf40  = nfl0 >> 2;
        const float* src = x + (size_t)cb_ * CHUNK * 7;
        for (int i = tid; i < nf40; i += BLOCK)
            gload16((const float4*)src + i, &buf[0][i * 4]);
        for (int i = (nf40 << 2) + tid; i < nfl0; i += BLOCK)
            gload4(src + i, &buf[0][i]);
    }
    // LDS narrow table: straight u32 copy of the pre-packed table.
    for (int i = tid; i < GPCK / 4; i += BLOCK)
        ((uint4*)tn)[i] = ((const uint4*)g2p)[i];
    __syncthreads();

    int cur = 0;
    for (int cc = cb_; cc < ce; ++cc) {
        if (cc + 1 < ce) {
            int rowsN = min(CHUNK, B - (cc + 1) * CHUNK);
            int nflN  = rowsN * 7;
            int nf4N  = nflN >> 2;
            const float* src = x + (size_t)(cc + 1) * CHUNK * 7;
            for (int i = tid; i < nf4N; i += BLOCK)
                gload16((const float4*)src + i, &buf[cur ^ 1][i * 4]);
            for (int i = (nf4N << 2) + tid; i < nflN; i += BLOCK)
                gload4(src + i, &buf[cur ^ 1][i]);
        }

        int rows = min(CHUNK, B - cc * CHUNK);
        float* bfr = buf[cur];
        for (int r = tid; r < rows; r += BLOCK) {
            float* row = bfr + r * 7;
            float x0 = row[0], x2 = row[2], x6 = row[6];
            float f = (x6 <= 0.f) ? (x6 + 1.f) : (1.f - x6);   // loop constant
            // step 1: wide packed table from global (8KB, L1-hot).
            {
                float p = fmaf(x2, f * IHW_, CW_);
                p = fminf(fmaxf(p, 0.f), (float)NW);
                int idx = (int)p; float fr = p - (float)idx;
                x2 = lerp_pk(g1p[idx], fr);
            }
            // steps 2..9: Clenshaw on VALU (t clamped to fit interval).
#pragma unroll
            for (int s = 0; s < 8; ++s) {
                float t = x2 * f;
                t = fminf(fmaxf(t, LO2), HI2);
                float u  = (t - MID2) * IHALF2;
                float u2 = u + u;
                float b1_ = 0.f, b2_ = 0.f;
#pragma unroll
                for (int k = NCOEF - 1; k >= 1; --k) {
                    float bn = fmaf(u2, b1_, c[k] - b2_);
                    b2_ = b1_; b1_ = bn;
                }
                x2 = fmaf(u, b1_, c[0] - b2_);
            }
            // step 10: LDS packed table + outputs.
            float t = x2 * f;
            float p = fmaf(t, IH2, C2);
            p = fminf(fmaxf(p, 0.f), (float)N2);
            int idx = (int)p; float fr = p - (float)idx;
            float x2f = lerp_pk(tn[idx], fr);
            float x4 = t + LAT_CONST;
            row[0] = x0 + 10.f;            // 10 steps of +1
            row[2] = x2f;
            row[3] = x4 * GRAD_CONST;
            row[4] = x4;
            row[5] = t * SEND_CONST;       // cols 1,6 pass through
        }
        __syncthreads();

        // Store chunk: LDS -> global, dense float4 + scalar remainder.
        {
            int nfl = rows * 7;
            int nf4 = nfl >> 2;
            float* dst = out + (size_t)cc * CHUNK * 7;
            const float4* s4 = (const float4*)bfr;
            for (int i = tid; i < nf4; i += BLOCK) ((float4*)dst)[i] = s4[i];
            for (int i = (nf4 << 2) + tid; i < nfl; i += BLOCK) dst[i] = bfr[i];
        }
        __syncthreads();
        cur ^= 1;
    }
}

static inline size_t align16h(size_t v) { return (v + 15) & ~(size_t)15; }

extern "C" void kernel_launch(void* const* d_in, const int* in_sizes, int n_in,
                              void* d_out, int out_size, void* d_ws, size_t ws_size,
                              hipStream_t stream)
{
    const float* x  = (const float*)d_in[0];
    const float* W1 = (const float*)d_in[1];
    const float* b1 = (const float*)d_in[2];
    const float* W2 = (const float*)d_in[3];
    const float* b2 = (const float*)d_in[4];
    const float* W3 = (const float*)d_in[5];
    const float* b3 = (const float*)d_in[6];
    float* out = (float*)d_out;

    int B = in_sizes[0] / 7;

    // ws: [g1 f32][g2 f32][g1p u32][g2p u32][fch 64 f32][cb 32 f32]
    char* ws = (char*)d_ws;
    size_t seg = align16h((size_t)GSZ * 4);
    float* g1  = (float*)ws;
    float* g2  = (float*)(ws + seg);
    u32*   g1p = (u32*)  (ws + 2 * seg);
    u32*   g2p = (u32*)  (ws + 3 * seg);
    float* fch = (float*)(ws + 4 * seg);
    float* cb  = (float*)(ws + 4 * seg + align16h(MCH * 4));

    int nChunks = (B + CHUNK - 1) / CHUNK;
    int grid    = (nChunks < MAXBLK) ? nChunks : MAXBLK;

    hipLaunchKernelGGL(build_table_kernel, dim3((2 * GSZ + MCH) / 64), dim3(512), 0, stream,
                       W1, b1, W2, b2, W3, b3, g1, g2, fch);
    hipLaunchKernelGGL(fit_pack_kernel, dim3((GPCK + 255) / 256), dim3(256), 0, stream,
                       g1, g2, fch, g1p, g2p, cb);
    hipLaunchKernelGGL(rows_kernel, dim3(grid), dim3(BLOCK), 0, stream,
                       x, g1p, g2p, cb, out, B, nChunks, grid);
}

// Round 15
// 34.666 us; speedup vs baseline: 1.5437x; 1.5437x over previous
//
#include <hip/hip_runtime.h>
#include <math.h>

#define LAT_CONST  ((float)(5.0 * 0.03 / 200.0 + 0.06))   // 0.06075
#define GRAD_CONST ((float)(1.0 / 0.06))                  // 16.666666...
#define SEND_CONST ((float)(2.0 / 3.0))                   // 0.666666...

// Wide table (step 1, global packed bf16 pairs): t = x2_init*f in [-24, 24].
#define NW   2048
#define LOW_ (-24.f)
#define HIW_ (24.f)
#define HW_  ((HIW_ - LOW_) / (float)NW)
#define IHW_ ((float)NW / (HIW_ - LOW_))
#define CW_  (-LOW_ * IHW_)
// Narrow range (steps 2..10): x2 in (0,1), f in (-5.8, 1].
#define N2   2048
#define LO2  (-6.25f)
#define HI2  (1.25f)
#define H2   ((HI2 - LO2) / (float)N2)
#define IH2  ((float)N2 / (HI2 - LO2))
#define C2   (-LO2 * IH2)
// Coarse narrow table (steps 2..9, LDS, 128 cells): kink lerp err ~6e-4/step,
// below the bf16 pack quantum -> precision unchanged, gathers ~broadcast-free.
#define NC   128
#define IHC  ((float)NC / (HI2 - LO2))        // 17.0667
#define CC   (-LO2 * IHC)                     // 106.667

#define GSZ   2080      // f32 entries built per table (padded)
#define GPCK  2064      // packed u32 wide entries (uses <= NW+1 = 2049)
#define NCP   132       // coarse packed entries (uses <= NC+1 = 129)
#define NPF   2052      // fine float2 pairs (uses <= N2+1 = 2049)

typedef unsigned int u32;

__device__ __forceinline__ u32 bfpack(float a, float b) {
    u32 ua = __float_as_uint(a), ub = __float_as_uint(b);
    ua = (ua + 0x7fffu + ((ua >> 16) & 1u)) >> 16;          // RNE to bf16
    ub = (ub + 0x7fffu + ((ub >> 16) & 1u)) & 0xffff0000u;  // RNE, keep high half
    return (ua & 0xffffu) | ub;
}

__device__ __forceinline__ float lerp_pk(u32 u, float fr) {
    float e0 = __uint_as_float(u << 16);
    float e1 = __uint_as_float(u & 0xffff0000u);
    return fmaf(e1 - e0, fr, e0);
}

// ---------------- Kernel 1: build both f32 tables ----------------
// 64 entries/block, layer-2 j-split across 8 waves (R13 structure).
__global__ __launch_bounds__(512)
void build_table_kernel(const float* __restrict__ W1, const float* __restrict__ b1,
                        const float* __restrict__ W2, const float* __restrict__ b2,
                        const float* __restrict__ W3, const float* __restrict__ b3,
                        float* __restrict__ g1, float* __restrict__ g2)
{
    __shared__ float pl[8][64];

    const int lane = threadIdx.x & 63;
    const int w    = threadIdx.x >> 6;                // 0..7
    const int i    = blockIdx.x * 64 + lane;          // 0 .. 2*GSZ-1

    float t;
    if (i < GSZ) t = LOW_ + (float)i * HW_;
    else         t = LO2 + (float)(i - GSZ) * H2;

    float x4 = t + LAT_CONST;
    float x5 = t * SEND_CONST;
    float x3 = x4 * GRAD_CONST;

    float h1v[64];
#pragma unroll
    for (int j = 0; j < 64; ++j) {
        float acc = b1[j];
        acc = fmaf(x3, W1[j],       acc);
        acc = fmaf(x4, W1[64 + j],  acc);
        acc = fmaf(x5, W1[128 + j], acc);
        h1v[j] = fmaxf(acc, 0.f);
    }

    const int j0 = w * 8;
    float acc[8];
#pragma unroll
    for (int u = 0; u < 8; ++u) acc[u] = b2[j0 + u];
#pragma unroll
    for (int k = 0; k < 64; ++k) {
        const float* __restrict__ w2r = W2 + k * 64 + j0;
#pragma unroll
        for (int u = 0; u < 8; ++u)
            acc[u] = fmaf(h1v[k], w2r[u], acc[u]);
    }
    float partial = 0.f;
#pragma unroll
    for (int u = 0; u < 8; ++u)
        partial = fmaf(fmaxf(acc[u], 0.f), W3[j0 + u], partial);

    pl[w][lane] = partial;
    __syncthreads();

    if (w == 0) {
        float logit = b3[0] + (((pl[0][lane] + pl[1][lane]) + (pl[2][lane] + pl[3][lane]))
                             + ((pl[4][lane] + pl[5][lane]) + (pl[6][lane] + pl[7][lane])));
        float g = 1.f / (1.f + expf(-logit));
        if (i < GSZ) g1[i] = g;
        else         g2[i - GSZ] = g;
    }
}

// ---------------- Kernel 1b: pack wide bf16 / coarse bf16 / fine f32 pairs --
__global__ __launch_bounds__(256)
void pack_table_kernel(const float* __restrict__ g1, const float* __restrict__ g2,
                       u32* __restrict__ g1p, u32* __restrict__ tcp,
                       float2* __restrict__ g2pf)
{
    int i = blockIdx.x * blockDim.x + threadIdx.x;
    if (i < GPCK) g1p[i] = bfpack(g1[i], g1[i + 1]);
    if (i < NPF)  g2pf[i] = make_float2(g2[i], g2[i + 1]);
    if (i <= NC)  tcp[i] = bfpack(g2[16 * i], g2[16 * i + 16]);   // coarse = every 16th fine
}

// ---------------- Kernel 2: persistent pipelined row update ----------------
// Steps 2..9 -> 520B LDS coarse table (broadcast-heavy, ~conflict-free);
// step 1 -> global packed wide (L1-hot 8KB); step 10 -> global fine f32
// pairs (L1-hot 16KB, one dwordx2, full f32 precision on the amplified path).
// LDS = 0.5 + 14.3 KB -> 8 blocks/CU = 32 waves (full occupancy cap).
#define CHUNK 256
#define BLOCK 256
#define MAXBLK 2048       // 8 blocks/CU * 256 CU

typedef __attribute__((address_space(3))) u32 lds_u32_t;
typedef __attribute__((address_space(1))) const u32 glb_u32_t;

__device__ __forceinline__ void gload16(const void* g, void* l) {
    __builtin_amdgcn_global_load_lds((glb_u32_t*)g, (lds_u32_t*)l, 16, 0, 0);
}
__device__ __forceinline__ void gload4(const void* g, void* l) {
    __builtin_amdgcn_global_load_lds((glb_u32_t*)g, (lds_u32_t*)l, 4, 0, 0);
}

__global__ __launch_bounds__(BLOCK)
void rows_kernel(const float* __restrict__ x, const u32* __restrict__ g1p,
                 const float2* __restrict__ g2pf, const u32* __restrict__ tcp,
                 float* __restrict__ out, int B, int nChunks, int grid)
{
    __shared__ u32 tc[NCP];                            // 528 B coarse table
    __shared__ __align__(16) float buf[2][CHUNK * 7];  // 14336 B (total ~14.9KB)

    const int tid = threadIdx.x;
    const long long b = blockIdx.x;
    const int cb = (int)(b * (long long)nChunks / grid);
    const int ce = (int)((b + 1) * (long long)nChunks / grid);

    // Prologue: async-DMA first chunk into buf0.
    {
        int rows0 = min(CHUNK, B - cb * CHUNK);
        int nfl0  = rows0 * 7;
        int nf40  = nfl0 >> 2;
        const float* src = x + (size_t)cb * CHUNK * 7;
        for (int i = tid; i < nf40; i += BLOCK)
            gload16((const float4*)src + i, &buf[0][i * 4]);
        for (int i = (nf40 << 2) + tid; i < nfl0; i += BLOCK)
            gload4(src + i, &buf[0][i]);
    }
    // Coarse table -> LDS (tiny straight copy).
    if (tid < NCP) tc[tid] = (tid <= NC) ? tcp[tid] : 0u;
    __syncthreads();

    int cur = 0;
    for (int c = cb; c < ce; ++c) {
        // Issue next chunk's staging DMA (lands during this chunk's compute).
        if (c + 1 < ce) {
            int rowsN = min(CHUNK, B - (c + 1) * CHUNK);
            int nflN  = rowsN * 7;
            int nf4N  = nflN >> 2;
            const float* src = x + (size_t)(c + 1) * CHUNK * 7;
            for (int i = tid; i < nf4N; i += BLOCK)
                gload16((const float4*)src + i, &buf[cur ^ 1][i * 4]);
            for (int i = (nf4N << 2) + tid; i < nflN; i += BLOCK)
                gload4(src + i, &buf[cur ^ 1][i]);
        }

        int rows = min(CHUNK, B - c * CHUNK);
        float* bfr = buf[cur];
        for (int r = tid; r < rows; r += BLOCK) {
            float* row = bfr + r * 7;                 // stride 7 dwords: 2/bank, free
            float x0 = row[0], x2 = row[2], x6 = row[6];
            float f = (x6 <= 0.f) ? (x6 + 1.f) : (1.f - x6);   // loop constant
            // step 1: wide packed table from global (8KB, L1-hot).
            {
                float p = fmaf(x2, f * IHW_, CW_);
                p = fminf(fmaxf(p, 0.f), (float)NW);
                int idx = (int)p; float fr = p - (float)idx;
                x2 = lerp_pk(g1p[idx], fr);
            }
            float afc = f * IHC;
            // steps 2..9: 128-cell coarse LDS table (broadcast-heavy gathers).
#pragma unroll
            for (int s = 0; s < 8; ++s) {
                float p = fmaf(x2, afc, CC);
                p = fminf(fmaxf(p, 0.f), (float)NC);
                int idx = (int)p; float fr = p - (float)idx;
                x2 = lerp_pk(tc[idx], fr);
            }
            // step 10: fine f32 pairs from global (16KB, L1-hot, one dwordx2).
            float t = x2 * f;
            float p = fmaf(t, IH2, C2);
            p = fminf(fmaxf(p, 0.f), (float)N2);
            int idx = (int)p; float fr = p - (float)idx;
            float2 e = g2pf[idx];
            float x2f = fmaf(e.y - e.x, fr, e.x);
            float x4 = t + LAT_CONST;
            row[0] = x0 + 10.f;            // 10 steps of +1
            row[2] = x2f;
            row[3] = x4 * GRAD_CONST;
            row[4] = x4;
            row[5] = t * SEND_CONST;       // cols 1,6 pass through
        }
        __syncthreads();

        // Store chunk: LDS -> global, dense float4 + scalar remainder.
        {
            int nfl = rows * 7;
            int nf4 = nfl >> 2;
            float* dst = out + (size_t)c * CHUNK * 7;
            const float4* s4 = (const float4*)bfr;
            for (int i = tid; i < nf4; i += BLOCK) ((float4*)dst)[i] = s4[i];
            for (int i = (nf4 << 2) + tid; i < nfl; i += BLOCK) dst[i] = bfr[i];
        }
        __syncthreads();
        cur ^= 1;
    }
}

static inline size_t align16h(size_t v) { return (v + 15) & ~(size_t)15; }

extern "C" void kernel_launch(void* const* d_in, const int* in_sizes, int n_in,
                              void* d_out, int out_size, void* d_ws, size_t ws_size,
                              hipStream_t stream)
{
    const float* x  = (const float*)d_in[0];
    const float* W1 = (const float*)d_in[1];
    const float* b1 = (const float*)d_in[2];
    const float* W2 = (const float*)d_in[3];
    const float* b2 = (const float*)d_in[4];
    const float* W3 = (const float*)d_in[5];
    const float* b3 = (const float*)d_in[6];
    float* out = (float*)d_out;

    int B = in_sizes[0] / 7;

    // ws: [g1 f32 GSZ][g2 f32 GSZ][g1p u32 GPCK][tcp u32 NCP][g2pf float2 NPF]
    char* ws = (char*)d_ws;
    size_t off = 0;
    float*  g1   = (float*)(ws + off); off += align16h((size_t)GSZ * 4);
    float*  g2   = (float*)(ws + off); off += align16h((size_t)GSZ * 4);
    u32*    g1p  = (u32*)  (ws + off); off += align16h((size_t)GPCK * 4);
    u32*    tcp  = (u32*)  (ws + off); off += align16h((size_t)NCP * 4);
    float2* g2pf = (float2*)(ws + off);

    int nChunks = (B + CHUNK - 1) / CHUNK;
    int grid    = (nChunks < MAXBLK) ? nChunks : MAXBLK;

    hipLaunchKernelGGL(build_table_kernel, dim3((2 * GSZ) / 64), dim3(512), 0, stream,
                       W1, b1, W2, b2, W3, b3, g1, g2);
    hipLaunchKernelGGL(pack_table_kernel, dim3((NPF + 255) / 256), dim3(256), 0, stream,
                       g1, g2, g1p, tcp, g2pf);
    hipLaunchKernelGGL(rows_kernel, dim3(grid), dim3(BLOCK), 0, stream,
                       x, g1p, g2pf, tcp, out, B, nChunks, grid);
}

// Round 16
// 34.445 us; speedup vs baseline: 1.5536x; 1.0064x over previous
//
#include <hip/hip_runtime.h>
#include <math.h>

#define LAT_CONST  ((float)(5.0 * 0.03 / 200.0 + 0.06))   // 0.06075
#define GRAD_CONST ((float)(1.0 / 0.06))                  // 16.666666...
#define SEND_CONST ((float)(2.0 / 3.0))                   // 0.666666...

// Wide coarse table (step 1, LDS bf16 pairs): 512 cells over [-24, 24].
// Kink lerp err ~1e-3 on step-1 x2; contractively propagated -> negligible.
#define NWC  512
#define LOW_ (-24.f)
#define HWC  (48.f / (float)NWC)
#define IHWC ((float)NWC / 48.f)              // 10.6667
#define CWC  (24.f * IHWC)                    // 256
// Narrow coarse table (steps 2..10, LDS bf16 pairs): 128 cells over [-6.25,1.25].
// x2 in (0,1) after step 1, f in (-5.8, 1]. Err/step ~ kink 6e-4 + bf16 2e-3;
// amplified x3 path (x16.7 via step 9) measured at absmax 0.125 in R15.
#define NCC  128
#define LO2  (-6.25f)
#define HI2  (1.25f)
#define H2C  ((HI2 - LO2) / (float)NCC)
#define IHC  ((float)NCC / (HI2 - LO2))       // 17.0667
#define CC   (-LO2 * IHC)                     // 106.667

#define WSZ 520      // wide f32 entries built (rows uses 0..513)
#define CSZ 136      // narrow f32 entries built (rows uses 0..129)

typedef unsigned int u32;

__device__ __forceinline__ u32 bfpack(float a, float b) {
    u32 ua = __float_as_uint(a), ub = __float_as_uint(b);
    ua = (ua + 0x7fffu + ((ua >> 16) & 1u)) >> 16;          // RNE to bf16
    ub = (ub + 0x7fffu + ((ub >> 16) & 1u)) & 0xffff0000u;  // RNE, keep high half
    return (ua & 0xffffu) | ub;
}

__device__ __forceinline__ float lerp_pk(u32 u, float fr) {
    float e0 = __uint_as_float(u << 16);
    float e1 = __uint_as_float(u & 0xffff0000u);
    return fmaf(e1 - e0, fr, e0);
}

// ---------------- Kernel 1: build both small f32 tables (656 entries) -------
// 64 entries/block, layer-2 j-split across 8 waves (proven R13 structure).
__global__ __launch_bounds__(512)
void build_table_kernel(const float* __restrict__ W1, const float* __restrict__ b1,
                        const float* __restrict__ W2, const float* __restrict__ b2,
                        const float* __restrict__ W3, const float* __restrict__ b3,
                        float* __restrict__ g1, float* __restrict__ g2)
{
    __shared__ float pl[8][64];

    const int lane = threadIdx.x & 63;
    const int w    = threadIdx.x >> 6;                // 0..7
    const int i    = blockIdx.x * 64 + lane;          // 0 .. WSZ+CSZ-1 (+pad)
    const int ie   = (i < WSZ + CSZ) ? i : (WSZ + CSZ - 1);

    float t;
    if (ie < WSZ) t = LOW_ + (float)ie * HWC;
    else          t = LO2 + (float)(ie - WSZ) * H2C;

    float x4 = t + LAT_CONST;
    float x5 = t * SEND_CONST;
    float x3 = x4 * GRAD_CONST;

    float h1v[64];
#pragma unroll
    for (int j = 0; j < 64; ++j) {
        float acc = b1[j];
        acc = fmaf(x3, W1[j],       acc);
        acc = fmaf(x4, W1[64 + j],  acc);
        acc = fmaf(x5, W1[128 + j], acc);
        h1v[j] = fmaxf(acc, 0.f);
    }

    const int j0 = w * 8;
    float acc[8];
#pragma unroll
    for (int u = 0; u < 8; ++u) acc[u] = b2[j0 + u];
#pragma unroll
    for (int k = 0; k < 64; ++k) {
        const float* __restrict__ w2r = W2 + k * 64 + j0;
#pragma unroll
        for (int u = 0; u < 8; ++u)
            acc[u] = fmaf(h1v[k], w2r[u], acc[u]);
    }
    float partial = 0.f;
#pragma unroll
    for (int u = 0; u < 8; ++u)
        partial = fmaf(fmaxf(acc[u], 0.f), W3[j0 + u], partial);

    pl[w][lane] = partial;
    __syncthreads();

    if (w == 0 && i < WSZ + CSZ) {
        float logit = b3[0] + (((pl[0][lane] + pl[1][lane]) + (pl[2][lane] + pl[3][lane]))
                             + ((pl[4][lane] + pl[5][lane]) + (pl[6][lane] + pl[7][lane])));
        float g = 1.f / (1.f + expf(-logit));
        if (i < WSZ) g1[i] = g;
        else         g2[i - WSZ] = g;
    }
}

// ---------------- Kernel 2: persistent pipelined row update ----------------
// ALL 10 lookups hit tiny LDS bf16-pair tables (2.6 KB total, broadcast-heavy)
// -> zero per-lane VMEM gathers; VMEM pipe is pure streaming (DMA in, f4 out).
// LDS = 2.1 + 0.5 + 14.3 KB = 16.9 KB -> 8 blocks/CU (32-wave cap).
#define CHUNK 256
#define BLOCK 256
#define MAXBLK 2048       // 8 blocks/CU * 256 CU

typedef __attribute__((address_space(3))) u32 lds_u32_t;
typedef __attribute__((address_space(1))) const u32 glb_u32_t;

__device__ __forceinline__ void gload16(const void* g, void* l) {
    __builtin_amdgcn_global_load_lds((glb_u32_t*)g, (lds_u32_t*)l, 16, 0, 0);
}
__device__ __forceinline__ void gload4(const void* g, void* l) {
    __builtin_amdgcn_global_load_lds((glb_u32_t*)g, (lds_u32_t*)l, 4, 0, 0);
}

__global__ __launch_bounds__(BLOCK)
void rows_kernel(const float* __restrict__ x, const float* __restrict__ g1,
                 const float* __restrict__ g2, float* __restrict__ out,
                 int B, int nChunks, int grid)
{
    __shared__ u32 tcw[NWC + 4];                       // 2064 B wide coarse
    __shared__ u32 tcn[NCC + 4];                       // 528 B narrow coarse
    __shared__ __align__(16) float buf[2][CHUNK * 7];  // 14336 B

    const int tid = threadIdx.x;
    const long long b = blockIdx.x;
    const int cb = (int)(b * (long long)nChunks / grid);
    const int ce = (int)((b + 1) * (long long)nChunks / grid);

    // Prologue: async-DMA first chunk into buf0 (lands under table packing).
    {
        int rows0 = min(CHUNK, B - cb * CHUNK);
        int nfl0  = rows0 * 7;
        int nf40  = nfl0 >> 2;
        const float* src = x + (size_t)cb * CHUNK * 7;
        for (int i = tid; i < nf40; i += BLOCK)
            gload16((const float4*)src + i, &buf[0][i * 4]);
        for (int i = (nf40 << 2) + tid; i < nfl0; i += BLOCK)
            gload4(src + i, &buf[0][i]);
    }
    // Pack both coarse tables from the L2-hot f32 builds (646 bfpacks/block).
    for (int i = tid; i < NWC + 2; i += BLOCK) tcw[i] = bfpack(g1[i], g1[i + 1]);
    for (int i = tid; i < NCC + 2; i += BLOCK) tcn[i] = bfpack(g2[i], g2[i + 1]);
    __syncthreads();   // tables ready + buf0 DMA drained

    int cur = 0;
    for (int c = cb; c < ce; ++c) {
        // Issue next chunk's staging DMA (lands during this chunk's compute).
        if (c + 1 < ce) {
            int rowsN = min(CHUNK, B - (c + 1) * CHUNK);
            int nflN  = rowsN * 7;
            int nf4N  = nflN >> 2;
            const float* src = x + (size_t)(c + 1) * CHUNK * 7;
            for (int i = tid; i < nf4N; i += BLOCK)
                gload16((const float4*)src + i, &buf[cur ^ 1][i * 4]);
            for (int i = (nf4N << 2) + tid; i < nflN; i += BLOCK)
                gload4(src + i, &buf[cur ^ 1][i]);
        }

        int rows = min(CHUNK, B - c * CHUNK);
        float* bfr = buf[cur];
        for (int r = tid; r < rows; r += BLOCK) {
            float* row = bfr + r * 7;                 // stride 7 dwords: 2/bank, free
            float x0 = row[0], x2 = row[2], x6 = row[6];
            float f = (x6 <= 0.f) ? (x6 + 1.f) : (1.f - x6);   // loop constant
            // step 1: wide coarse LDS table.
            {
                float p = fmaf(x2, f * IHWC, CWC);
                p = fminf(fmaxf(p, 0.f), (float)NWC);
                int idx = (int)p; float fr = p - (float)idx;
                x2 = lerp_pk(tcw[idx], fr);
            }
            float afc = f * IHC;
            // steps 2..9: narrow coarse LDS table.
#pragma unroll
            for (int s = 0; s < 8; ++s) {
                float p = fmaf(x2, afc, CC);
                p = fminf(fmaxf(p, 0.f), (float)NCC);
                int idx = (int)p; float fr = p - (float)idx;
                x2 = lerp_pk(tcn[idx], fr);
            }
            // step 10 (same narrow table) + outputs.
            float t = x2 * f;
            float p = fmaf(t, IHC, CC);
            p = fminf(fmaxf(p, 0.f), (float)NCC);
            int idx = (int)p; float fr = p - (float)idx;
            float x2f = lerp_pk(tcn[idx], fr);
            float x4 = t + LAT_CONST;
            row[0] = x0 + 10.f;            // 10 steps of +1
            row[2] = x2f;
            row[3] = x4 * GRAD_CONST;
            row[4] = x4;
            row[5] = t * SEND_CONST;       // cols 1,6 pass through
        }
        __syncthreads();   // results visible (also drains next-chunk DMA)

        // Store chunk: LDS -> global, dense float4 + scalar remainder.
        {
            int nfl = rows * 7;
            int nf4 = nfl >> 2;
            float* dst = out + (size_t)c * CHUNK * 7;
            const float4* s4 = (const float4*)bfr;
            for (int i = tid; i < nf4; i += BLOCK) ((float4*)dst)[i] = s4[i];
            for (int i = (nf4 << 2) + tid; i < nfl; i += BLOCK) dst[i] = bfr[i];
        }
        __syncthreads();   // store reads done before bfr is re-staged
        cur ^= 1;
    }
}

static inline size_t align16h(size_t v) { return (v + 15) & ~(size_t)15; }

extern "C" void kernel_launch(void* const* d_in, const int* in_sizes, int n_in,
                              void* d_out, int out_size, void* d_ws, size_t ws_size,
                              hipStream_t stream)
{
    const float* x  = (const float*)d_in[0];
    const float* W1 = (const float*)d_in[1];
    const float* b1 = (const float*)d_in[2];
    const float* W2 = (const float*)d_in[3];
    const float* b2 = (const float*)d_in[4];
    const float* W3 = (const float*)d_in[5];
    const float* b3 = (const float*)d_in[6];
    float* out = (float*)d_out;

    int B = in_sizes[0] / 7;

    // ws: [g1 f32 WSZ][g2 f32 CSZ]
    char* ws = (char*)d_ws;
    float* g1 = (float*)ws;
    float* g2 = (float*)(ws + align16h((size_t)WSZ * 4));

    int nChunks = (B + CHUNK - 1) / CHUNK;
    int grid    = (nChunks < MAXBLK) ? nChunks : MAXBLK;

    hipLaunchKernelGGL(build_table_kernel, dim3((WSZ + CSZ + 63) / 64), dim3(512), 0, stream,
                       W1, b1, W2, b2, W3, b3, g1, g2);
    hipLaunchKernelGGL(rows_kernel, dim3(grid), dim3(BLOCK), 0, stream,
                       x, g1, g2, out, B, nChunks, grid);
}